// Round 1
// baseline (119.268 us; speedup 1.0000x reference)
//
#include <hip/hip_runtime.h>
#include <hip/hip_bf16.h>

// Chamfer distance, B=4, N=M=8192, D=3, fp32.
// d2(p,t) = |p|^2 + (|t|^2 - 2 p.t). Stage DB points as (-2x,-2y,-2z,|t|^2)
// float4 in LDS; each thread register-blocks Q=8 query points; DB split 16-way
// across blocks; partial mins combined via uint-bitpattern atomicMin (d2>=0).

#define T 256      // threads per block
#define Q 8        // query points per thread
#define S 16       // db splits
#define CH 512     // db chunk size (8192 / S)
#define NPTS 8192
#define NCOMBO 8   // 2 directions x 4 batches

__global__ __launch_bounds__(T) void chamfer_partial(
    const float* __restrict__ pred, const float* __restrict__ target,
    unsigned int* __restrict__ partmin)
{
    __shared__ float4 db[CH + 2];  // +2 pad so prefetch never branches

    const int bid   = blockIdx.x;
    const int dbc   = bid & (S - 1);        // db chunk
    const int qc    = (bid >> 4) & 3;       // query chunk (2048 queries each)
    const int combo = bid >> 6;             // 0..7
    const int dir   = combo & 1;
    const int b     = combo >> 1;

    const float* qptr = (dir == 0 ? pred : target) + (size_t)b * NPTS * 3;
    const float* dptr = (dir == 0 ? target : pred) + (size_t)b * NPTS * 3;

    const int tid = threadIdx.x;

    // --- stage db chunk into LDS, transformed ---
    for (int p = tid; p < CH; p += T) {
        int gj = dbc * CH + p;
        float x = dptr[gj * 3 + 0];
        float y = dptr[gj * 3 + 1];
        float z = dptr[gj * 3 + 2];
        db[p] = make_float4(-2.f * x, -2.f * y, -2.f * z,
                            x * x + y * y + z * z);
    }

    // --- load Q query points into registers ---
    float qx[Q], qy[Q], qz[Q], m[Q];
    int qi0 = qc * (T * Q) + tid;
#pragma unroll
    for (int k = 0; k < Q; k++) {
        int qi = qi0 + k * T;
        qx[k] = qptr[qi * 3 + 0];
        qy[k] = qptr[qi * 3 + 1];
        qz[k] = qptr[qi * 3 + 2];
        m[k]  = 3.4e38f;
    }
    __syncthreads();

    // --- main loop: unroll 2, 1-deep prefetch to hide ds_read latency ---
    float4 c0 = db[0], c1 = db[1];
    for (int j = 0; j < CH; j += 2) {
        float4 n0 = db[j + 2];
        float4 n1 = db[j + 3];
#pragma unroll
        for (int k = 0; k < Q; k++) {
            float s0 = fmaf(c0.x, qx[k], fmaf(c0.y, qy[k], fmaf(c0.z, qz[k], c0.w)));
            float s1 = fmaf(c1.x, qx[k], fmaf(c1.y, qy[k], fmaf(c1.z, qz[k], c1.w)));
            m[k] = fminf(m[k], fminf(s0, s1));
        }
        c0 = n0; c1 = n1;
    }

    // --- epilogue: add |q|^2, clamp >=0, atomicMin on bit pattern ---
#pragma unroll
    for (int k = 0; k < Q; k++) {
        int qi = qi0 + k * T;
        float qq = fmaf(qx[k], qx[k], fmaf(qy[k], qy[k], qz[k] * qz[k]));
        float d2 = fmaxf(m[k] + qq, 0.0f);
        atomicMin(&partmin[combo * NPTS + qi], __float_as_uint(d2));
    }
}

__global__ __launch_bounds__(1024) void reduce_final(
    const unsigned int* __restrict__ partmin,
    const float* __restrict__ bpp, const float* __restrict__ lamda,
    float* __restrict__ out)
{
    const int tid = threadIdx.x;
    float s = 0.f;
#pragma unroll
    for (int k = 0; k < (NCOMBO * NPTS) / 1024; k++)
        s += __uint_as_float(partmin[tid + k * 1024]);

    // wave(64) reduce
#pragma unroll
    for (int off = 32; off > 0; off >>= 1)
        s += __shfl_down(s, off, 64);

    __shared__ float red[16];
    int lane = tid & 63, wid = tid >> 6;
    if (lane == 0) red[wid] = s;
    __syncthreads();
    if (wid == 0) {
        s = (lane < 16) ? red[lane] : 0.f;
#pragma unroll
        for (int off = 8; off > 0; off >>= 1)
            s += __shfl_down(s, off, 64);
        if (lane == 0)
            out[0] = s * (1.0f / 32768.0f) + lamda[0] * bpp[0];
    }
}

extern "C" void kernel_launch(void* const* d_in, const int* in_sizes, int n_in,
                              void* d_out, int out_size, void* d_ws, size_t ws_size,
                              hipStream_t stream) {
    const float* pred   = (const float*)d_in[0];
    const float* target = (const float*)d_in[1];
    const float* bpp    = (const float*)d_in[2];
    const float* lamda  = (const float*)d_in[3];
    unsigned int* partmin = (unsigned int*)d_ws;

    // init partial mins to a huge positive float (0x7F7F7F7F ~ 3.39e38)
    hipMemsetAsync(partmin, 0x7F, NCOMBO * NPTS * sizeof(unsigned int), stream);

    chamfer_partial<<<NCOMBO * 4 * S, T, 0, stream>>>(pred, target, partmin);
    reduce_final<<<1, 1024, 0, stream>>>(partmin, bpp, lamda, (float*)d_out);
}